// Round 3
// baseline (1149.066 us; speedup 1.0000x reference)
//
#include <hip/hip_runtime.h>
#include <stdint.h>

// L=512, B=32, D=H=256
// Workspace layout (floats):
//   Eq  [16384*256] @ 0         (exp2(C2*xq))
//   Ev  [16384*256] @ 4194304   (exp2(C2*xv))
//   S   [32*512*512] @ 8388608  (scores, then softmax in place)
//   C   [16384*256] @ 0         (context, reuses Eq region - dead after score_k)
//   Gi  [16384*768] @ 4194304   (input gates, reuses Ev+S regions - dead after ctx_k)
// Total: 16777216 floats = 64 MB

#define C2    2.8853900817779268f   // 2*log2(e)
#define LOG2E 1.4426950408889634f

typedef __fp16 f16x2 __attribute__((ext_vector_type(2)));

static __device__ __forceinline__ float rcp_f(float x)  { return __builtin_amdgcn_rcpf(x); }
static __device__ __forceinline__ float exp2_f(float x) { return __builtin_amdgcn_exp2f(x); }
static __device__ __forceinline__ uint32_t pk16(float a, float b) {
  f16x2 p = __builtin_amdgcn_cvt_pkrtz(a, b);
  return __builtin_bit_cast(uint32_t, p);
}
static __device__ __forceinline__ float dot2f(uint32_t a, uint32_t b, float c) {
  return __builtin_amdgcn_fdot2(__builtin_bit_cast(f16x2, a),
                                __builtin_bit_cast(f16x2, b), c, false);
}

// ---------------------------------------------------------------------------
// out[m][n] = epilogue( sum_d A[m][d] * W[n][d] ),  K = 256 fixed
// expmode=1: out = exp2(C2 * acc)   (bias unused)
// expmode=0: out = acc + bias[n]
// grid: (N/64, M/64), block: 256
// ---------------------------------------------------------------------------
__global__ __launch_bounds__(256) void gemm_nt(
    const float* __restrict__ A, const float* __restrict__ W,
    const float* __restrict__ bias, float* __restrict__ out,
    int N, int expmode)
{
  __shared__ __align__(16) float As[32][68];
  __shared__ __align__(16) float Ws[32][68];
  const int t = threadIdx.x;
  const int tx = t & 15, ty = t >> 4;
  const int n0 = blockIdx.x * 64, m0 = blockIdx.y * 64;
  float acc[4][4] = {};

  for (int k0 = 0; k0 < 256; k0 += 32) {
#pragma unroll
    for (int s = 0; s < 2; ++s) {
      int f = t + s * 256;
      int row = f >> 3, kq = f & 7;
      float4 a = *(const float4*)&A[(size_t)(m0 + row) * 256 + k0 + kq * 4];
      float4 w = *(const float4*)&W[(size_t)(n0 + row) * 256 + k0 + kq * 4];
      As[kq * 4 + 0][row] = a.x; As[kq * 4 + 1][row] = a.y;
      As[kq * 4 + 2][row] = a.z; As[kq * 4 + 3][row] = a.w;
      Ws[kq * 4 + 0][row] = w.x; Ws[kq * 4 + 1][row] = w.y;
      Ws[kq * 4 + 2][row] = w.z; Ws[kq * 4 + 3][row] = w.w;
    }
    __syncthreads();
#pragma unroll
    for (int kk = 0; kk < 32; ++kk) {
      float4 a4 = *(const float4*)&As[kk][ty * 4];
      float4 b4 = *(const float4*)&Ws[kk][tx * 4];
      float av[4] = {a4.x, a4.y, a4.z, a4.w};
      float bv[4] = {b4.x, b4.y, b4.z, b4.w};
#pragma unroll
      for (int r = 0; r < 4; ++r)
#pragma unroll
        for (int c = 0; c < 4; ++c)
          acc[r][c] = fmaf(av[r], bv[c], acc[r][c]);
    }
    __syncthreads();
  }

#pragma unroll
  for (int r = 0; r < 4; ++r) {
    float4 o;
    if (expmode) {
      o.x = exp2_f(C2 * acc[r][0]); o.y = exp2_f(C2 * acc[r][1]);
      o.z = exp2_f(C2 * acc[r][2]); o.w = exp2_f(C2 * acc[r][3]);
    } else {
      float4 bb = *(const float4*)&bias[n0 + tx * 4];
      o.x = acc[r][0] + bb.x; o.y = acc[r][1] + bb.y;
      o.z = acc[r][2] + bb.z; o.w = acc[r][3] + bb.w;
    }
    *(float4*)&out[(size_t)(m0 + ty * 4 + r) * N + n0 + tx * 4] = o;
  }
}

// ---------------------------------------------------------------------------
// S[b][i][l] = -2 * sum_h Vvec[b][h] * rcp(1 + Eq[i][b][h]*Ev[l][b][h])
// (true score differs by +sumV[b], constant over l -> softmax-invariant)
// grid: (512/32 l-tiles, 512/64 i-tiles, 32 b), block 256 (tx=16 l, ty=16 i)
// per thread: 4 i-rows x 2 l-cols; inner loop in explicit float4 (b128 LDS)
// ---------------------------------------------------------------------------
__global__ __launch_bounds__(256) void score_k(
    const float* __restrict__ Eq, const float* __restrict__ Ev,
    const float* __restrict__ Vvec, float* __restrict__ S)
{
  __shared__ __align__(16) float Eqs[64][68];
  __shared__ __align__(16) float Evs[32][68];
  __shared__ __align__(16) float Vs[256];
  const int t = threadIdx.x;
  const int tx = t & 15, ty = t >> 4;
  const int l0 = blockIdx.x * 32;
  const int i0 = blockIdx.y * 64;
  const int b  = blockIdx.z;

  Vs[t] = -2.0f * Vvec[b * 256 + t];
  float acc[4][2] = {};

  for (int st = 0; st < 4; ++st) {
    const int h0 = st * 64;
#pragma unroll
    for (int s = 0; s < 4; ++s) {
      int f = t + s * 256;
      int row = f >> 4, cq = f & 15;
      *(float4*)&Eqs[row][cq * 4] =
          *(const float4*)&Eq[((size_t)(i0 + row) * 32 + b) * 256 + h0 + cq * 4];
    }
#pragma unroll
    for (int s = 0; s < 2; ++s) {
      int f = t + s * 256;
      int row = f >> 4, cq = f & 15;
      *(float4*)&Evs[row][cq * 4] =
          *(const float4*)&Ev[((size_t)(l0 + row) * 32 + b) * 256 + h0 + cq * 4];
    }
    __syncthreads();
#pragma unroll 4
    for (int k4 = 0; k4 < 16; ++k4) {
      float4 vh = *(const float4*)&Vs[h0 + k4 * 4];
      float4 e0 = *(const float4*)&Evs[tx][k4 * 4];
      float4 e1 = *(const float4*)&Evs[tx + 16][k4 * 4];
#pragma unroll
      for (int r = 0; r < 4; ++r) {
        float4 eq = *(const float4*)&Eqs[ty * 4 + r][k4 * 4];
        acc[r][0] += vh.x * rcp_f(fmaf(eq.x, e0.x, 1.0f));
        acc[r][0] += vh.y * rcp_f(fmaf(eq.y, e0.y, 1.0f));
        acc[r][0] += vh.z * rcp_f(fmaf(eq.z, e0.z, 1.0f));
        acc[r][0] += vh.w * rcp_f(fmaf(eq.w, e0.w, 1.0f));
        acc[r][1] += vh.x * rcp_f(fmaf(eq.x, e1.x, 1.0f));
        acc[r][1] += vh.y * rcp_f(fmaf(eq.y, e1.y, 1.0f));
        acc[r][1] += vh.z * rcp_f(fmaf(eq.z, e1.z, 1.0f));
        acc[r][1] += vh.w * rcp_f(fmaf(eq.w, e1.w, 1.0f));
      }
    }
    __syncthreads();
  }

#pragma unroll
  for (int r = 0; r < 4; ++r) {
    float* ps = &S[((size_t)b * 512 + i0 + ty * 4 + r) * 512 + l0];
    ps[tx]      = acc[r][0];
    ps[tx + 16] = acc[r][1];
  }
}

// ---------------------------------------------------------------------------
// In-place softmax over last dim (512) of S viewed as [16384][512].
// grid: 16384 blocks of 64 (one wave per row)
// ---------------------------------------------------------------------------
__global__ __launch_bounds__(64) void softmax_k(float* __restrict__ S)
{
  const int t = threadIdx.x;
  float* row = &S[(size_t)blockIdx.x * 512];
  float x[8];
  float m = -1e30f;
#pragma unroll
  for (int u = 0; u < 8; ++u) { x[u] = row[t + u * 64]; m = fmaxf(m, x[u]); }
#pragma unroll
  for (int o = 32; o; o >>= 1) m = fmaxf(m, __shfl_xor(m, o, 64));
  float sum = 0.f;
#pragma unroll
  for (int u = 0; u < 8; ++u) { x[u] = exp2_f(LOG2E * (x[u] - m)); sum += x[u]; }
#pragma unroll
  for (int o = 32; o; o >>= 1) sum += __shfl_xor(sum, o, 64);
  float inv = rcp_f(sum);
#pragma unroll
  for (int u = 0; u < 8; ++u) row[t + u * 64] = x[u] * inv;
}

// ---------------------------------------------------------------------------
// C[i][b][d] = sum_l A[b][i][l] * v[l][b][d]
// grid: (256/64 d-tiles, 512/64 i-tiles, 32 b), block 256
// ---------------------------------------------------------------------------
__global__ __launch_bounds__(256) void ctx_k(
    const float* __restrict__ Aw, const float* __restrict__ v,
    float* __restrict__ C)
{
  __shared__ __align__(16) float As[32][68];
  __shared__ __align__(16) float Vs[32][68];
  const int t = threadIdx.x, tx = t & 15, ty = t >> 4;
  const int d0 = blockIdx.x * 64, i0 = blockIdx.y * 64, b = blockIdx.z;
  float acc[4][4] = {};

  for (int l0 = 0; l0 < 512; l0 += 32) {
#pragma unroll
    for (int s = 0; s < 2; ++s) {
      int f = t + s * 256;
      int row = f >> 3, lq = f & 7;
      float4 a = *(const float4*)&Aw[((size_t)b * 512 + i0 + row) * 512 + l0 + lq * 4];
      As[lq * 4 + 0][row] = a.x; As[lq * 4 + 1][row] = a.y;
      As[lq * 4 + 2][row] = a.z; As[lq * 4 + 3][row] = a.w;
    }
#pragma unroll
    for (int s = 0; s < 2; ++s) {
      int f = t + s * 256;
      int row = f >> 4, dq = f & 15;
      *(float4*)&Vs[row][dq * 4] =
          *(const float4*)&v[((size_t)(l0 + row) * 32 + b) * 256 + d0 + dq * 4];
    }
    __syncthreads();
#pragma unroll
    for (int kk = 0; kk < 32; ++kk) {
      float4 a4 = *(const float4*)&As[kk][ty * 4];
      float4 b4 = *(const float4*)&Vs[kk][tx * 4];
      float av[4] = {a4.x, a4.y, a4.z, a4.w};
      float bv[4] = {b4.x, b4.y, b4.z, b4.w};
#pragma unroll
      for (int r = 0; r < 4; ++r)
#pragma unroll
        for (int c = 0; c < 4; ++c)
          acc[r][c] = fmaf(av[r], bv[c], acc[r][c]);
    }
    __syncthreads();
  }

#pragma unroll
  for (int r = 0; r < 4; ++r) {
    float4 o = {acc[r][0], acc[r][1], acc[r][2], acc[r][3]};
    *(float4*)&C[((size_t)(i0 + ty * 4 + r) * 32 + b) * 256 + d0 + tx * 4] = o;
  }
}

// ---------------------------------------------------------------------------
// Sequential GRU, one block per batch. 1024 threads: j = t&255, q = t>>8
// (k-quarter). Thread holds W_hh rows {j, j+256, j+512} for its 64-wide
// k-quarter as packed f16 in 96 VGPRs (fits the 128-VGPR cap of a 1024-thread
// block -> no AGPR round-trips). Gi loads software-pipelined one step ahead;
// h double-buffered in LDS as f16 (2 barriers/step).
// grid: 32, block 1024
// ---------------------------------------------------------------------------
__global__ __launch_bounds__(1024) void gru_k(
    const float* __restrict__ Gi, const float* __restrict__ Whh,
    const float* __restrict__ bhh, const float* __restrict__ h0,
    float* __restrict__ out)
{
  __shared__ float part[12][256];
  __shared__ __align__(16) _Float16 hbuf[2][256];
  const int t = threadIdx.x, j = t & 255, q = t >> 8, b = blockIdx.x;

  // weights: gate rows {j, j+256, j+512}, k in [q*64, q*64+64), packed f16
  uint32_t wpk[3][32];
#pragma unroll
  for (int g = 0; g < 3; ++g) {
    const float4* wp = (const float4*)&Whh[(size_t)(j + g * 256) * 256 + q * 64];
#pragma unroll
    for (int c = 0; c < 16; ++c) {
      float4 w = wp[c];
      wpk[g][c * 2]     = pk16(w.x, w.y);
      wpk[g][c * 2 + 1] = pk16(w.z, w.w);
    }
  }

  float h_old = 0.f, br = 0.f, bz = 0.f, bn = 0.f;
  float gr = 0.f, gz = 0.f, gn = 0.f;
  if (t < 256) {
    h_old = h0[b * 256 + j];
    hbuf[0][j] = (_Float16)h_old;
    br = bhh[j]; bz = bhh[256 + j]; bn = bhh[512 + j];
    const float* gp = &Gi[(size_t)b * 768 + j];   // i = 0
    gr = gp[0]; gz = gp[256]; gn = gp[512];
  }
  __syncthreads();

  for (int i = 0; i < 512; ++i) {
    // prefetch Gi for next step (latency hidden under the dot loop)
    float ngr = 0.f, ngz = 0.f, ngn = 0.f;
    {
      int ip = (i + 1 < 512) ? (i + 1) : 511;
      if (t < 256) {
        const float* gp = &Gi[((size_t)ip * 32 + b) * 768 + j];
        ngr = gp[0]; ngz = gp[256]; ngn = gp[512];
      }
    }
    // dot over my k-quarter
    const uint4* h4 = (const uint4*)hbuf[i & 1] + q * 8;
    float a0 = 0.f, a1 = 0.f, a2 = 0.f;
#pragma unroll
    for (int c = 0; c < 8; ++c) {
      uint4 hh = h4[c];
      uint32_t hx[4] = {hh.x, hh.y, hh.z, hh.w};
#pragma unroll
      for (int u = 0; u < 4; ++u) {
        a0 = dot2f(wpk[0][c * 4 + u], hx[u], a0);
        a1 = dot2f(wpk[1][c * 4 + u], hx[u], a1);
        a2 = dot2f(wpk[2][c * 4 + u], hx[u], a2);
      }
    }
    part[q * 3 + 0][j] = a0;
    part[q * 3 + 1][j] = a1;
    part[q * 3 + 2][j] = a2;
    __syncthreads();
    if (t < 256) {
      float ghr = part[0][j] + part[3][j] + part[6][j] + part[9][j]  + br;
      float ghz = part[1][j] + part[4][j] + part[7][j] + part[10][j] + bz;
      float ghn = part[2][j] + part[5][j] + part[8][j] + part[11][j] + bn;
      float r = rcp_f(1.0f + exp2_f(-LOG2E * (gr + ghr)));
      float z = rcp_f(1.0f + exp2_f(-LOG2E * (gz + ghz)));
      float na = fmaf(r, ghn, gn);
      float n = fmaf(-2.0f, rcp_f(1.0f + exp2_f(C2 * na)), 1.0f);  // tanh(na)
      float hnew = fmaf(z, h_old - n, n);
      h_old = hnew;
      out[((size_t)i * 32 + b) * 256 + j] = hnew;
      hbuf[(i + 1) & 1][j] = (_Float16)hnew;
    }
    gr = ngr; gz = ngz; gn = ngn;
    __syncthreads();
  }
}

// ---------------------------------------------------------------------------
extern "C" void kernel_launch(void* const* d_in, const int* in_sizes, int n_in,
                              void* d_out, int out_size, void* d_ws, size_t ws_size,
                              hipStream_t stream)
{
  const float* v   = (const float*)d_in[0];
  const float* h0  = (const float*)d_in[1];
  const float* Vv  = (const float*)d_in[2];
  const float* Wp  = (const float*)d_in[3];
  const float* Wp_ = (const float*)d_in[4];
  const float* Wih = (const float*)d_in[5];
  const float* Whh = (const float*)d_in[6];
  const float* bih = (const float*)d_in[7];
  const float* bhh = (const float*)d_in[8];
  float* out = (float*)d_out;
  float* ws  = (float*)d_ws;

  float* Eq = ws;
  float* Ev = ws + 4194304;
  float* S  = ws + 8388608;
  float* C  = ws;            // reuse Eq region (dead after score_k)
  float* Gi = ws + 4194304;  // reuse Ev + S regions (dead after ctx_k)

  // projections + exp2 epilogue: Eq, Ev  [16384 x 256]
  gemm_nt<<<dim3(4, 256), 256, 0, stream>>>(v, Wp,  nullptr, Eq, 256, 1);
  gemm_nt<<<dim3(4, 256), 256, 0, stream>>>(v, Wp_, nullptr, Ev, 256, 1);
  // scores S[b][i][l]
  score_k<<<dim3(16, 8, 32), 256, 0, stream>>>(Eq, Ev, Vv, S);
  // softmax over l, in place
  softmax_k<<<16384, 64, 0, stream>>>(S);
  // context C[i][b][d]
  ctx_k<<<dim3(4, 8, 32), 256, 0, stream>>>(S, v, C);
  // input gates Gi[i*32+b][768] = C @ W_ih^T + b_ih
  gemm_nt<<<dim3(12, 256), 256, 0, stream>>>(C, Wih, bih, Gi, 768, 0);
  // sequential GRU -> out
  gru_k<<<32, 1024, 0, stream>>>(Gi, Whh, bhh, h0, out);
}

// Round 4
// 1087.321 us; speedup vs baseline: 1.0568x; 1.0568x over previous
//
#include <hip/hip_runtime.h>
#include <stdint.h>

// L=512, B=32, D=H=256
// Workspace layout (floats):
//   Eq  [16384*256] @ 0         (exp2(C2*xq))
//   Ev  [16384*256] @ 4194304   (exp2(C2*xv))
//   S   [32*512*512] @ 8388608  (scores, then softmax in place)
//   C   [16384*256] @ 0         (context, reuses Eq region - dead after score_k)
//   Gi  [16384*768] @ 4194304   (input gates, reuses Ev+S regions - dead after ctx_k)
// Total: 16777216 floats = 64 MB

#define C2    2.8853900817779268f   // 2*log2(e)
#define LOG2E 1.4426950408889634f

typedef __fp16 f16x2 __attribute__((ext_vector_type(2)));

static __device__ __forceinline__ float rcp_f(float x)  { return __builtin_amdgcn_rcpf(x); }
static __device__ __forceinline__ float exp2_f(float x) { return __builtin_amdgcn_exp2f(x); }
static __device__ __forceinline__ uint32_t pk16(float a, float b) {
  f16x2 p = __builtin_amdgcn_cvt_pkrtz(a, b);
  return __builtin_bit_cast(uint32_t, p);
}
static __device__ __forceinline__ float dot2f(uint32_t a, uint32_t b, float c) {
  return __builtin_amdgcn_fdot2(__builtin_bit_cast(f16x2, a),
                                __builtin_bit_cast(f16x2, b), c, false);
}

// ---------------------------------------------------------------------------
// out[m][n] = epilogue( sum_d A[m][d] * W[n][d] ),  K = 256 fixed
// expmode=1: out = exp2(C2 * acc)   (bias unused)
// expmode=0: out = acc + bias[n]
// grid: (N/64, M/64), block: 256
// ---------------------------------------------------------------------------
__global__ __launch_bounds__(256) void gemm_nt(
    const float* __restrict__ A, const float* __restrict__ W,
    const float* __restrict__ bias, float* __restrict__ out,
    int N, int expmode)
{
  __shared__ __align__(16) float As[32][68];
  __shared__ __align__(16) float Ws[32][68];
  const int t = threadIdx.x;
  const int tx = t & 15, ty = t >> 4;
  const int n0 = blockIdx.x * 64, m0 = blockIdx.y * 64;
  float acc[4][4] = {};

  for (int k0 = 0; k0 < 256; k0 += 32) {
#pragma unroll
    for (int s = 0; s < 2; ++s) {
      int f = t + s * 256;
      int row = f >> 3, kq = f & 7;
      float4 a = *(const float4*)&A[(size_t)(m0 + row) * 256 + k0 + kq * 4];
      float4 w = *(const float4*)&W[(size_t)(n0 + row) * 256 + k0 + kq * 4];
      As[kq * 4 + 0][row] = a.x; As[kq * 4 + 1][row] = a.y;
      As[kq * 4 + 2][row] = a.z; As[kq * 4 + 3][row] = a.w;
      Ws[kq * 4 + 0][row] = w.x; Ws[kq * 4 + 1][row] = w.y;
      Ws[kq * 4 + 2][row] = w.z; Ws[kq * 4 + 3][row] = w.w;
    }
    __syncthreads();
#pragma unroll
    for (int kk = 0; kk < 32; ++kk) {
      float4 a4 = *(const float4*)&As[kk][ty * 4];
      float4 b4 = *(const float4*)&Ws[kk][tx * 4];
      float av[4] = {a4.x, a4.y, a4.z, a4.w};
      float bv[4] = {b4.x, b4.y, b4.z, b4.w};
#pragma unroll
      for (int r = 0; r < 4; ++r)
#pragma unroll
        for (int c = 0; c < 4; ++c)
          acc[r][c] = fmaf(av[r], bv[c], acc[r][c]);
    }
    __syncthreads();
  }

#pragma unroll
  for (int r = 0; r < 4; ++r) {
    float4 o;
    if (expmode) {
      o.x = exp2_f(C2 * acc[r][0]); o.y = exp2_f(C2 * acc[r][1]);
      o.z = exp2_f(C2 * acc[r][2]); o.w = exp2_f(C2 * acc[r][3]);
    } else {
      float4 bb = *(const float4*)&bias[n0 + tx * 4];
      o.x = acc[r][0] + bb.x; o.y = acc[r][1] + bb.y;
      o.z = acc[r][2] + bb.z; o.w = acc[r][3] + bb.w;
    }
    *(float4*)&out[(size_t)(m0 + ty * 4 + r) * N + n0 + tx * 4] = o;
  }
}

// ---------------------------------------------------------------------------
// S[b][i][l] = -2 * sum_h Vvec[b][h] * rcp(1 + Eq[i][b][h]*Ev[l][b][h])
// grid: (512/32 l-tiles, 512/64 i-tiles, 32 b), block 256 (tx=16 l, ty=16 i)
// ---------------------------------------------------------------------------
__global__ __launch_bounds__(256) void score_k(
    const float* __restrict__ Eq, const float* __restrict__ Ev,
    const float* __restrict__ Vvec, float* __restrict__ S)
{
  __shared__ __align__(16) float Eqs[64][68];
  __shared__ __align__(16) float Evs[32][68];
  __shared__ __align__(16) float Vs[256];
  const int t = threadIdx.x;
  const int tx = t & 15, ty = t >> 4;
  const int l0 = blockIdx.x * 32;
  const int i0 = blockIdx.y * 64;
  const int b  = blockIdx.z;

  Vs[t] = -2.0f * Vvec[b * 256 + t];
  float acc[4][2] = {};

  for (int st = 0; st < 4; ++st) {
    const int h0 = st * 64;
#pragma unroll
    for (int s = 0; s < 4; ++s) {
      int f = t + s * 256;
      int row = f >> 4, cq = f & 15;
      *(float4*)&Eqs[row][cq * 4] =
          *(const float4*)&Eq[((size_t)(i0 + row) * 32 + b) * 256 + h0 + cq * 4];
    }
#pragma unroll
    for (int s = 0; s < 2; ++s) {
      int f = t + s * 256;
      int row = f >> 4, cq = f & 15;
      *(float4*)&Evs[row][cq * 4] =
          *(const float4*)&Ev[((size_t)(l0 + row) * 32 + b) * 256 + h0 + cq * 4];
    }
    __syncthreads();
#pragma unroll 4
    for (int k4 = 0; k4 < 16; ++k4) {
      float4 vh = *(const float4*)&Vs[h0 + k4 * 4];
      float4 e0 = *(const float4*)&Evs[tx][k4 * 4];
      float4 e1 = *(const float4*)&Evs[tx + 16][k4 * 4];
#pragma unroll
      for (int r = 0; r < 4; ++r) {
        float4 eq = *(const float4*)&Eqs[ty * 4 + r][k4 * 4];
        acc[r][0] += vh.x * rcp_f(fmaf(eq.x, e0.x, 1.0f));
        acc[r][0] += vh.y * rcp_f(fmaf(eq.y, e0.y, 1.0f));
        acc[r][0] += vh.z * rcp_f(fmaf(eq.z, e0.z, 1.0f));
        acc[r][0] += vh.w * rcp_f(fmaf(eq.w, e0.w, 1.0f));
        acc[r][1] += vh.x * rcp_f(fmaf(eq.x, e1.x, 1.0f));
        acc[r][1] += vh.y * rcp_f(fmaf(eq.y, e1.y, 1.0f));
        acc[r][1] += vh.z * rcp_f(fmaf(eq.z, e1.z, 1.0f));
        acc[r][1] += vh.w * rcp_f(fmaf(eq.w, e1.w, 1.0f));
      }
    }
    __syncthreads();
  }

#pragma unroll
  for (int r = 0; r < 4; ++r) {
    float* ps = &S[((size_t)b * 512 + i0 + ty * 4 + r) * 512 + l0];
    ps[tx]      = acc[r][0];
    ps[tx + 16] = acc[r][1];
  }
}

// ---------------------------------------------------------------------------
// In-place softmax over last dim (512) of S viewed as [16384][512].
// ---------------------------------------------------------------------------
__global__ __launch_bounds__(64) void softmax_k(float* __restrict__ S)
{
  const int t = threadIdx.x;
  float* row = &S[(size_t)blockIdx.x * 512];
  float x[8];
  float m = -1e30f;
#pragma unroll
  for (int u = 0; u < 8; ++u) { x[u] = row[t + u * 64]; m = fmaxf(m, x[u]); }
#pragma unroll
  for (int o = 32; o; o >>= 1) m = fmaxf(m, __shfl_xor(m, o, 64));
  float sum = 0.f;
#pragma unroll
  for (int u = 0; u < 8; ++u) { x[u] = exp2_f(LOG2E * (x[u] - m)); sum += x[u]; }
#pragma unroll
  for (int o = 32; o; o >>= 1) sum += __shfl_xor(sum, o, 64);
  float inv = rcp_f(sum);
#pragma unroll
  for (int u = 0; u < 8; ++u) row[t + u * 64] = x[u] * inv;
}

// ---------------------------------------------------------------------------
// C[i][b][d] = sum_l A[b][i][l] * v[l][b][d]
// ---------------------------------------------------------------------------
__global__ __launch_bounds__(256) void ctx_k(
    const float* __restrict__ Aw, const float* __restrict__ v,
    float* __restrict__ C)
{
  __shared__ __align__(16) float As[32][68];
  __shared__ __align__(16) float Vs[32][68];
  const int t = threadIdx.x, tx = t & 15, ty = t >> 4;
  const int d0 = blockIdx.x * 64, i0 = blockIdx.y * 64, b = blockIdx.z;
  float acc[4][4] = {};

  for (int l0 = 0; l0 < 512; l0 += 32) {
#pragma unroll
    for (int s = 0; s < 2; ++s) {
      int f = t + s * 256;
      int row = f >> 3, lq = f & 7;
      float4 a = *(const float4*)&Aw[((size_t)b * 512 + i0 + row) * 512 + l0 + lq * 4];
      As[lq * 4 + 0][row] = a.x; As[lq * 4 + 1][row] = a.y;
      As[lq * 4 + 2][row] = a.z; As[lq * 4 + 3][row] = a.w;
    }
#pragma unroll
    for (int s = 0; s < 2; ++s) {
      int f = t + s * 256;
      int row = f >> 4, dq = f & 15;
      *(float4*)&Vs[row][dq * 4] =
          *(const float4*)&v[((size_t)(l0 + row) * 32 + b) * 256 + d0 + dq * 4];
    }
    __syncthreads();
#pragma unroll
    for (int kk = 0; kk < 32; ++kk) {
      float4 a4 = *(const float4*)&As[kk][ty * 4];
      float4 b4 = *(const float4*)&Vs[kk][tx * 4];
      float av[4] = {a4.x, a4.y, a4.z, a4.w};
      float bv[4] = {b4.x, b4.y, b4.z, b4.w};
#pragma unroll
      for (int r = 0; r < 4; ++r)
#pragma unroll
        for (int c = 0; c < 4; ++c)
          acc[r][c] = fmaf(av[r], bv[c], acc[r][c]);
    }
    __syncthreads();
  }

#pragma unroll
  for (int r = 0; r < 4; ++r) {
    float4 o = {acc[r][0], acc[r][1], acc[r][2], acc[r][3]};
    *(float4*)&C[((size_t)(i0 + ty * 4 + r) * 32 + b) * 256 + d0 + tx * 4] = o;
  }
}

// ---------------------------------------------------------------------------
// Sequential GRU, one block per batch. 512 threads: j = t&255, half = t>>8.
// Thread holds W_hh rows {j, j+256, j+512} for its 128-wide k-half as packed
// f16 in 192 VGPRs. amdgpu_waves_per_eu(2,2) pins the unified register
// budget at 256/thread (2 waves x 256 = the full 512-reg SIMD file), so the
// whole array stays in ARCH VGPRs -- v_dot2 reads it directly, no
// accvgpr_read round-trips (the R2/R3 pathology: VGPR_Count 128/64 < array
// size => upper-half placement => 2x VALU ops per dot).
// grid: 32, block 512
// ---------------------------------------------------------------------------
__global__ __attribute__((amdgpu_flat_work_group_size(512, 512),
                          amdgpu_waves_per_eu(2, 2)))
void gru_k(
    const float* __restrict__ Gi, const float* __restrict__ Whh,
    const float* __restrict__ bhh, const float* __restrict__ h0,
    float* __restrict__ out)
{
  __shared__ float part[6][256];
  __shared__ __align__(16) _Float16 hbuf[2][256];
  const int t = threadIdx.x, j = t & 255, half = t >> 8, b = blockIdx.x;

  uint32_t wpk[3][64];
#pragma unroll
  for (int g = 0; g < 3; ++g) {
    const float4* wp = (const float4*)&Whh[(size_t)(j + g * 256) * 256 + half * 128];
#pragma unroll
    for (int c = 0; c < 32; ++c) {
      float4 w = wp[c];
      wpk[g][c * 2]     = pk16(w.x, w.y);
      wpk[g][c * 2 + 1] = pk16(w.z, w.w);
    }
  }

  float h_old = 0.f, br = 0.f, bz = 0.f, bn = 0.f;
  float gr = 0.f, gz = 0.f, gn = 0.f;
  if (t < 256) {
    h_old = h0[b * 256 + j];
    hbuf[0][j] = (_Float16)h_old;
    br = bhh[j]; bz = bhh[256 + j]; bn = bhh[512 + j];
    const float* gp = &Gi[(size_t)b * 768 + j];   // i = 0
    gr = gp[0]; gz = gp[256]; gn = gp[512];
  }
  __syncthreads();

  for (int i = 0; i < 512; ++i) {
    // prefetch Gi for next step (latency hidden under the dot loop)
    float ngr = 0.f, ngz = 0.f, ngn = 0.f;
    {
      int ip = (i + 1 < 512) ? (i + 1) : 511;
      if (t < 256) {
        const float* gp = &Gi[((size_t)ip * 32 + b) * 768 + j];
        ngr = gp[0]; ngz = gp[256]; ngn = gp[512];
      }
    }
    // dot over my 128-wide k-half: 16 uniform b128 reads, each feeding 12 dot2
    const uint4* h4 = (const uint4*)hbuf[i & 1] + half * 16;
    float a0 = 0.f, a1 = 0.f, a2 = 0.f;
#pragma unroll
    for (int c = 0; c < 16; ++c) {
      uint4 hh = h4[c];
      uint32_t hx[4] = {hh.x, hh.y, hh.z, hh.w};
#pragma unroll
      for (int u = 0; u < 4; ++u) {
        a0 = dot2f(wpk[0][c * 4 + u], hx[u], a0);
        a1 = dot2f(wpk[1][c * 4 + u], hx[u], a1);
        a2 = dot2f(wpk[2][c * 4 + u], hx[u], a2);
      }
    }
    part[half * 3 + 0][j] = a0;
    part[half * 3 + 1][j] = a1;
    part[half * 3 + 2][j] = a2;
    __syncthreads();
    if (t < 256) {
      float ghr = part[0][j] + part[3][j] + br;
      float ghz = part[1][j] + part[4][j] + bz;
      float ghn = part[2][j] + part[5][j] + bn;
      float r = rcp_f(1.0f + exp2_f(-LOG2E * (gr + ghr)));
      float z = rcp_f(1.0f + exp2_f(-LOG2E * (gz + ghz)));
      float na = fmaf(r, ghn, gn);
      float n = fmaf(-2.0f, rcp_f(1.0f + exp2_f(C2 * na)), 1.0f);  // tanh(na)
      float hnew = fmaf(z, h_old - n, n);
      h_old = hnew;
      out[((size_t)i * 32 + b) * 256 + j] = hnew;
      hbuf[(i + 1) & 1][j] = (_Float16)hnew;
    }
    gr = ngr; gz = ngz; gn = ngn;
    __syncthreads();
  }
}

// ---------------------------------------------------------------------------
extern "C" void kernel_launch(void* const* d_in, const int* in_sizes, int n_in,
                              void* d_out, int out_size, void* d_ws, size_t ws_size,
                              hipStream_t stream)
{
  const float* v   = (const float*)d_in[0];
  const float* h0  = (const float*)d_in[1];
  const float* Vv  = (const float*)d_in[2];
  const float* Wp  = (const float*)d_in[3];
  const float* Wp_ = (const float*)d_in[4];
  const float* Wih = (const float*)d_in[5];
  const float* Whh = (const float*)d_in[6];
  const float* bih = (const float*)d_in[7];
  const float* bhh = (const float*)d_in[8];
  float* out = (float*)d_out;
  float* ws  = (float*)d_ws;

  float* Eq = ws;
  float* Ev = ws + 4194304;
  float* S  = ws + 8388608;
  float* C  = ws;            // reuse Eq region (dead after score_k)
  float* Gi = ws + 4194304;  // reuse Ev + S regions (dead after ctx_k)

  gemm_nt<<<dim3(4, 256), 256, 0, stream>>>(v, Wp,  nullptr, Eq, 256, 1);
  gemm_nt<<<dim3(4, 256), 256, 0, stream>>>(v, Wp_, nullptr, Ev, 256, 1);
  score_k<<<dim3(16, 8, 32), 256, 0, stream>>>(Eq, Ev, Vv, S);
  softmax_k<<<16384, 64, 0, stream>>>(S);
  ctx_k<<<dim3(4, 8, 32), 256, 0, stream>>>(S, v, C);
  gemm_nt<<<dim3(12, 256), 256, 0, stream>>>(C, Wih, bih, Gi, 768, 0);
  gru_k<<<32, 512, 0, stream>>>(Gi, Whh, bhh, h0, out);
}